// Round 1
// baseline (231.644 us; speedup 1.0000x reference)
//
#include <hip/hip_runtime.h>
#include <hip/hip_bf16.h>

// ---------------------------------------------------------------------------
// Problem constants (from reference):
//   x: (2,32,32,768) fp32 -> flattened M=2048 rows of 768
//   w_qkv: (1280,768), w_out: (768,768)
//   q_heads=12, kv_heads=4, D_HEAD=64, KSIZE=7 (49 neighbors), GQA h -> h%4
// ---------------------------------------------------------------------------

#define NPIX 2048

// C[M,N] = A[M,K] @ B[N,K]^T   (both operands K-contiguous, row-major)
// Tiles: BM=BN=64, BK=16, 256 threads, 4x4 micro-tile per thread.
// Requires M%64==0, N%64==0, K%16==0 (true for all our shapes).
__global__ __launch_bounds__(256) void gemm_nt_kernel(
    const float* __restrict__ A, const float* __restrict__ B,
    float* __restrict__ C, int M, int N, int K)
{
    __shared__ float As[16][64];   // [k][m] — transposed for coalesced frag reads
    __shared__ float Bs[16][64];   // [k][n]
    const int tid = threadIdx.x;
    const int bm = blockIdx.y * 64;
    const int bn = blockIdx.x * 64;
    const int tm = (tid >> 4) * 4;     // 0..60
    const int tn = (tid & 15) * 4;     // 0..60
    const int lr = tid >> 2;           // 0..63  (row within tile for loads)
    const int lc = (tid & 3) * 4;      // 0,4,8,12 (k-offset for loads)

    float acc[4][4];
    #pragma unroll
    for (int i = 0; i < 4; i++)
        #pragma unroll
        for (int j = 0; j < 4; j++) acc[i][j] = 0.f;

    const float* Aptr = A + (size_t)(bm + lr) * K + lc;
    const float* Bptr = B + (size_t)(bn + lr) * K + lc;

    for (int k0 = 0; k0 < K; k0 += 16) {
        float4 a = *(const float4*)(Aptr + k0);
        float4 b = *(const float4*)(Bptr + k0);
        As[lc + 0][lr] = a.x; As[lc + 1][lr] = a.y;
        As[lc + 2][lr] = a.z; As[lc + 3][lr] = a.w;
        Bs[lc + 0][lr] = b.x; Bs[lc + 1][lr] = b.y;
        Bs[lc + 2][lr] = b.z; Bs[lc + 3][lr] = b.w;
        __syncthreads();
        #pragma unroll
        for (int kk = 0; kk < 16; kk++) {
            float4 av = *(const float4*)&As[kk][tm];   // 16B-aligned, bcast/2-way
            float4 bv = *(const float4*)&Bs[kk][tn];
            float am[4] = {av.x, av.y, av.z, av.w};
            float bn_[4] = {bv.x, bv.y, bv.z, bv.w};
            #pragma unroll
            for (int i = 0; i < 4; i++)
                #pragma unroll
                for (int j = 0; j < 4; j++)
                    acc[i][j] = fmaf(am[i], bn_[j], acc[i][j]);
        }
        __syncthreads();
    }
    #pragma unroll
    for (int i = 0; i < 4; i++) {
        float4 r = {acc[i][0], acc[i][1], acc[i][2], acc[i][3]};
        *(float4*)&C[(size_t)(bm + tm + i) * N + bn + tn] = r;
    }
}

// NATTEN 7x7 with GQA. One 192-thread block per (pixel m, kv-head g).
// Wave w (0..2) handles q-head h = g + 4w (tile-GQA: q-head h uses kv-head h%4).
// qkv layout: row m of 1280 floats = [q 0..767 | k 768..1023 | v 1024..1279].
// LDS pitch 65: word addr r*65+e -> bank (r+e)%32 -> worst 2-way (free, m136).
__global__ __launch_bounds__(192) void natten_kernel(
    const float* __restrict__ qkv, float* __restrict__ o)
{
    __shared__ float k_lds[49 * 65];
    __shared__ float v_lds[49 * 65];
    const int blk = blockIdx.x;
    const int g = blk & 3;         // kv head
    const int m = blk >> 2;        // pixel 0..2047
    const int n = m >> 10;
    const int i = (m >> 5) & 31;
    const int j = m & 31;
    const int si = min(max(i - 3, 0), 25);   // clip(i-3, 0, H-7)
    const int sj = min(max(j - 3, 0), 25);
    const int lane = threadIdx.x & 63;
    const int wave = threadIdx.x >> 6;

    // Stage 49 K rows + 49 V rows (64 contiguous floats each, coalesced 256B).
    for (int r = wave; r < 49; r += 3) {
        const int rm = (n << 10) + ((si + r / 7) << 5) + (sj + r % 7);
        const float* base = qkv + (size_t)rm * 1280 + 768 + g * 64;
        k_lds[r * 65 + lane] = base[lane];          // k
        v_lds[r * 65 + lane] = base[256 + lane];    // v (offset 1024-768=256)
    }
    __syncthreads();

    const int h = g + 4 * wave;                     // q head
    const float qv = qkv[(size_t)m * 1280 + h * 64 + lane] * 0.125f; // 1/sqrt(64)

    // Logits: lane jj (<49) computes dot(q, k[jj]) via shuffle-broadcast of q.
    const int jr = (lane < 49) ? lane : 48;         // clamp to stay in bounds
    float acc = 0.f;
    #pragma unroll
    for (int e = 0; e < 64; e++) {
        float qe = __shfl(qv, e);
        acc = fmaf(qe, k_lds[jr * 65 + e], acc);
    }

    // Softmax over 49 neighbors (lanes >=49 masked out).
    float lg = (lane < 49) ? acc : -1e30f;
    float mx = lg;
    #pragma unroll
    for (int off = 32; off; off >>= 1) mx = fmaxf(mx, __shfl_xor(mx, off));
    float p = (lane < 49) ? __expf(lg - mx) : 0.f;
    float s = p;
    #pragma unroll
    for (int off = 32; off; off >>= 1) s += __shfl_xor(s, off);
    p = p / s;

    // Output: lane e accumulates sum_j p_j * v[j][e].
    float oe = 0.f;
    for (int jj = 0; jj < 49; jj++) {
        float pj = __shfl(p, jj);
        oe = fmaf(pj, v_lds[jj * 65 + lane], oe);
    }
    o[(size_t)m * 768 + h * 64 + lane] = oe;
}

extern "C" void kernel_launch(void* const* d_in, const int* in_sizes, int n_in,
                              void* d_out, int out_size, void* d_ws, size_t ws_size,
                              hipStream_t stream)
{
    const float* x     = (const float*)d_in[0];   // (2048, 768)
    const float* w_qkv = (const float*)d_in[1];   // (1280, 768)
    const float* w_out = (const float*)d_in[2];   // (768, 768)
    float* out = (float*)d_out;                   // (2048, 768)

    float* qkv = (float*)d_ws;                    // 2048*1280 fp32 = 10.5 MB
    float* o   = qkv + (size_t)NPIX * 1280;       // 2048*768  fp32 =  6.3 MB

    // 1) qkv = x @ w_qkv^T
    gemm_nt_kernel<<<dim3(1280 / 64, NPIX / 64), dim3(256), 0, stream>>>(
        x, w_qkv, qkv, NPIX, 1280, 768);
    // 2) neighborhood attention
    natten_kernel<<<dim3(NPIX * 4), dim3(192), 0, stream>>>(qkv, o);
    // 3) out = o @ w_out^T
    gemm_nt_kernel<<<dim3(768 / 64, NPIX / 64), dim3(256), 0, stream>>>(
        o, w_out, out, NPIX, 768, 768);
}

// Round 2
// 156.522 us; speedup vs baseline: 1.4799x; 1.4799x over previous
//
#include <hip/hip_runtime.h>
#include <hip/hip_bf16.h>

// ---------------------------------------------------------------------------
// NattenBlock: qkv GEMM -> 7x7 neighborhood attention (GQA 12q/4kv, D=64)
//              -> out GEMM.  M=2048 pixels, d_model=768, qkv dim 1280.
// Round 2: both GEMMs as bf16 MFMA (m97 structure: 128x128 tile,
// global_load_lds width-16, 16x16x32 bf16 MFMA, fp32 accum). Attention
// stays fp32 (softmax precision), emits bf16 o directly for GEMM2.
// ---------------------------------------------------------------------------

#define NPIX 2048

typedef __attribute__((ext_vector_type(8))) __bf16 bf16x8;
typedef __attribute__((ext_vector_type(4))) float floatx4;

__device__ inline unsigned short f2bf(float f) {
    union { float f; unsigned u; } v; v.f = f;
    unsigned r = (v.u + 0x7fff + ((v.u >> 16) & 1)) >> 16;   // RNE
    return (unsigned short)r;
}

__device__ inline void gl_lds16(const void* g, void* l) {
    __builtin_amdgcn_global_load_lds(
        (const __attribute__((address_space(1))) void*)g,
        (__attribute__((address_space(3))) void*)l, 16, 0, 0);
}

// Convert x (393216 f4), w_qkv (245760 f4), w_out (147456 f4) to bf16.
__global__ __launch_bounds__(256) void convert_kernel(
    const float* __restrict__ x, const float* __restrict__ w1,
    const float* __restrict__ w2, unsigned short* __restrict__ xb,
    unsigned short* __restrict__ w1b, unsigned short* __restrict__ w2b)
{
    int t = blockIdx.x * blockDim.x + threadIdx.x;   // 0..786431
    const float* s; unsigned short* d;
    if (t < 393216)      { s = x;  d = xb; }
    else if (t < 638976) { s = w1; d = w1b; t -= 393216; }
    else                 { s = w2; d = w2b; t -= 638976; }
    float4 v = ((const float4*)s)[t];
    ushort4 o;
    o.x = f2bf(v.x); o.y = f2bf(v.y); o.z = f2bf(v.z); o.w = f2bf(v.w);
    ((ushort4*)d)[t] = o;
}

// C[M,N] (fp32) = A[M,K] @ B[N,K]^T, A/B bf16 (as ushort), K%32==0,
// M%128==0, N%128==0.  m97 structure: 128x128 tile, BK=32, 256 thr = 4 waves,
// each wave a 64x64 quadrant = 4x4 MFMA tiles of 16x16x32.
__global__ __launch_bounds__(256) void gemm_nt_mfma(
    const unsigned short* __restrict__ A, const unsigned short* __restrict__ B,
    float* __restrict__ C, int M, int N, int K)
{
    __shared__ unsigned short As[128 * 32];   // [m][k] row-major, no pad
    __shared__ unsigned short Bs[128 * 32];   // [n][k]
    const int tid = threadIdx.x;
    const int lane = tid & 63;
    const int wave = tid >> 6;
    const int bm = blockIdx.y * 128;
    const int bn = blockIdx.x * 128;
    const int qr = (wave >> 1) * 64;
    const int qc = (wave & 1) * 64;

    floatx4 acc[4][4] = {};

    // Staging: tile = 8 KB = 8 chunks of 1 KB; wave w stages chunks 2w,2w+1
    // of both As and Bs. Chunk c = rows [16c,16c+16); lane: row 16c+(l>>2),
    // k-elems (l&3)*8 .. +8  (16 B). LDS dest = uniform chunk base + lane*16.
    const int srow0 = wave * 32 + (lane >> 2);
    const int srow1 = srow0 + 16;
    const int skel  = (lane & 3) * 8;
    const unsigned short* Ap0 = A + (size_t)(bm + srow0) * K + skel;
    const unsigned short* Ap1 = A + (size_t)(bm + srow1) * K + skel;
    const unsigned short* Bp0 = B + (size_t)(bn + srow0) * K + skel;
    const unsigned short* Bp1 = B + (size_t)(bn + srow1) * K + skel;
    unsigned short* AsC0 = &As[(wave * 2 + 0) * 512];
    unsigned short* AsC1 = &As[(wave * 2 + 1) * 512];
    unsigned short* BsC0 = &Bs[(wave * 2 + 0) * 512];
    unsigned short* BsC1 = &Bs[(wave * 2 + 1) * 512];

    const int fr = lane & 15;          // m/n within 16-tile
    const int fk = (lane >> 4) * 8;    // k offset within BK=32

    for (int k0 = 0; k0 < K; k0 += 32) {
        gl_lds16(Ap0 + k0, AsC0);
        gl_lds16(Ap1 + k0, AsC1);
        gl_lds16(Bp0 + k0, BsC0);
        gl_lds16(Bp1 + k0, BsC1);
        __syncthreads();   // drains vmcnt (compiler emits) -> LDS valid
        bf16x8 af[4], bf[4];
        #pragma unroll
        for (int i = 0; i < 4; i++)
            af[i] = *(const bf16x8*)&As[(qr + i * 16 + fr) * 32 + fk];
        #pragma unroll
        for (int j = 0; j < 4; j++)
            bf[j] = *(const bf16x8*)&Bs[(qc + j * 16 + fr) * 32 + fk];
        #pragma unroll
        for (int i = 0; i < 4; i++)
            #pragma unroll
            for (int j = 0; j < 4; j++)
                acc[i][j] = __builtin_amdgcn_mfma_f32_16x16x32_bf16(
                    af[i], bf[j], acc[i][j], 0, 0, 0);
        __syncthreads();   // protect LDS from next iter's staging
    }

    // C/D layout: col = lane&15, row = (lane>>4)*4 + r   [m89/m91]
    const int cr = (lane >> 4) * 4;
    const int cc = lane & 15;
    #pragma unroll
    for (int i = 0; i < 4; i++)
        #pragma unroll
        for (int j = 0; j < 4; j++)
            #pragma unroll
            for (int r = 0; r < 4; r++)
                C[(size_t)(bm + qr + i * 16 + cr + r) * N + (bn + qc + j * 16 + cc)]
                    = acc[i][j][r];
}

// NATTEN 7x7 with GQA, fp32. One 192-thr block per (pixel m, kv-head g);
// wave w handles q-head h = g + 4w. Emits bf16 o for GEMM2.
__global__ __launch_bounds__(192) void natten_kernel(
    const float* __restrict__ qkv, unsigned short* __restrict__ o)
{
    __shared__ float k_lds[49 * 65];
    __shared__ float v_lds[49 * 65];
    const int blk = blockIdx.x;
    const int g = blk & 3;
    const int m = blk >> 2;
    const int n = m >> 10;
    const int i = (m >> 5) & 31;
    const int j = m & 31;
    const int si = min(max(i - 3, 0), 25);
    const int sj = min(max(j - 3, 0), 25);
    const int lane = threadIdx.x & 63;
    const int wave = threadIdx.x >> 6;

    for (int r = wave; r < 49; r += 3) {
        const int rm = (n << 10) + ((si + r / 7) << 5) + (sj + r % 7);
        const float* base = qkv + (size_t)rm * 1280 + 768 + g * 64;
        k_lds[r * 65 + lane] = base[lane];
        v_lds[r * 65 + lane] = base[256 + lane];
    }
    __syncthreads();

    const int h = g + 4 * wave;
    const float qv = qkv[(size_t)m * 1280 + h * 64 + lane] * 0.125f;

    const int jr = (lane < 49) ? lane : 48;
    float acc = 0.f;
    #pragma unroll
    for (int e = 0; e < 64; e++) {
        float qe = __shfl(qv, e);
        acc = fmaf(qe, k_lds[jr * 65 + e], acc);
    }

    float lg = (lane < 49) ? acc : -1e30f;
    float mx = lg;
    #pragma unroll
    for (int off = 32; off; off >>= 1) mx = fmaxf(mx, __shfl_xor(mx, off));
    float p = (lane < 49) ? __expf(lg - mx) : 0.f;
    float s = p;
    #pragma unroll
    for (int off = 32; off; off >>= 1) s += __shfl_xor(s, off);
    p = p / s;

    float oe = 0.f;
    for (int jj = 0; jj < 49; jj++) {
        float pj = __shfl(p, jj);
        oe = fmaf(pj, v_lds[jj * 65 + lane], oe);
    }
    o[(size_t)m * 768 + h * 64 + lane] = f2bf(oe);
}

extern "C" void kernel_launch(void* const* d_in, const int* in_sizes, int n_in,
                              void* d_out, int out_size, void* d_ws, size_t ws_size,
                              hipStream_t stream)
{
    const float* x     = (const float*)d_in[0];   // (2048, 768)
    const float* w_qkv = (const float*)d_in[1];   // (1280, 768)
    const float* w_out = (const float*)d_in[2];   // (768, 768)
    float* out = (float*)d_out;                   // (2048, 768)

    char* ws = (char*)d_ws;
    float*          qkv  = (float*)ws;                         ws += (size_t)NPIX * 1280 * 4; // 10.5 MB
    unsigned short* xb   = (unsigned short*)ws;                ws += (size_t)NPIX * 768 * 2;  //  3.1 MB
    unsigned short* w1b  = (unsigned short*)ws;                ws += (size_t)1280 * 768 * 2;  //  2.0 MB
    unsigned short* w2b  = (unsigned short*)ws;                ws += (size_t)768 * 768 * 2;   //  1.2 MB
    unsigned short* ob   = (unsigned short*)ws;                                               //  3.1 MB

    // 0) fp32 -> bf16 for GEMM operands
    convert_kernel<<<dim3(3072), dim3(256), 0, stream>>>(x, w_qkv, w_out, xb, w1b, w2b);
    // 1) qkv = x @ w_qkv^T   (bf16 MFMA, fp32 out)
    gemm_nt_mfma<<<dim3(1280 / 128, NPIX / 128), dim3(256), 0, stream>>>(
        xb, w1b, qkv, NPIX, 1280, 768);
    // 2) neighborhood attention (fp32, emits bf16 o)
    natten_kernel<<<dim3(NPIX * 4), dim3(192), 0, stream>>>(qkv, ob);
    // 3) out = o @ w_out^T
    gemm_nt_mfma<<<dim3(768 / 128, NPIX / 128), dim3(256), 0, stream>>>(
        ob, w2b, out, NPIX, 768, 768);
}

// Round 3
// 123.111 us; speedup vs baseline: 1.8816x; 1.2714x over previous
//
#include <hip/hip_runtime.h>
#include <hip/hip_bf16.h>

// ---------------------------------------------------------------------------
// NattenBlock: qkv GEMM -> 7x7 neighborhood attention (GQA 12q/4kv, D=64)
//              -> out GEMM.  2048 pixels (2x32x32), d_model 768.
// Round 3: natten rewritten on MFMA (8x8 query tile x 14x14 kv window,
// n = a*16+b indexing, O^T = V^T P^T with vT emitted by GEMM1 epilogue).
// GEMMs retiled 128x64 for 2x grid occupancy; qkv kept bf16 end-to-end.
// ---------------------------------------------------------------------------

typedef __attribute__((ext_vector_type(8))) __bf16 bf16x8;
typedef __attribute__((ext_vector_type(4))) float floatx4;
typedef unsigned short u16;

__device__ inline u16 f2bf(float f) {
    union { float f; unsigned u; } v; v.f = f;
    return (u16)((v.u + 0x7fff + ((v.u >> 16) & 1)) >> 16);   // RNE
}

__device__ inline void gl_lds16(const void* g, void* l) {
    __builtin_amdgcn_global_load_lds(
        (const __attribute__((address_space(1))) void*)g,
        (__attribute__((address_space(3))) void*)l, 16, 0, 0);
}

// fp32 -> bf16 for x (393216 f4), w_qkv (245760 f4), w_out (147456 f4).
__global__ __launch_bounds__(256) void convert_kernel(
    const float* __restrict__ x, const float* __restrict__ w1,
    const float* __restrict__ w2, u16* __restrict__ xb,
    u16* __restrict__ w1b, u16* __restrict__ w2b)
{
    int t = blockIdx.x * blockDim.x + threadIdx.x;   // 0..786431
    const float* s; u16* d;
    if (t < 393216)      { s = x;  d = xb; }
    else if (t < 638976) { s = w1; d = w1b; t -= 393216; }
    else                 { s = w2; d = w2b; t -= 638976; }
    float4 v = ((const float4*)s)[t];
    ushort4 o;
    o.x = f2bf(v.x); o.y = f2bf(v.y); o.z = f2bf(v.z); o.w = f2bf(v.w);
    ((ushort4*)d)[t] = o;
}

// C = A[M,K] @ B[N,K]^T, bf16 inputs, fp32 accum. Tile 128Mx64N, BK=32,
// 256 thr = 4 waves, wave quadrant 64x32 (4x2 MFMA tiles of 16x16x32).
// MODE 0: fp32 C[M,N].  MODE 1 (qkv GEMM): cols<1024 -> bf16 Cb[row*1024+col]
// (q|k), cols>=1024 -> transposed bf16 vT[(col-1024)*2048 + row] (one ushort4
// per acc tile: C-layout holds 4 consecutive rows per lane).
template<int MODE>
__global__ __launch_bounds__(256) void gemm_nt(
    const u16* __restrict__ A, const u16* __restrict__ B,
    float* __restrict__ C, u16* __restrict__ Cb, u16* __restrict__ vT,
    int M, int N, int K)
{
    __shared__ __align__(16) u16 As[128 * 32];
    __shared__ __align__(16) u16 Bs[64 * 32];
    const int tid = threadIdx.x;
    const int lane = tid & 63;
    const int wave = tid >> 6;
    const int bm = blockIdx.y * 128;
    const int bn = blockIdx.x * 64;
    const int qr = (wave >> 1) * 64;
    const int qc = (wave & 1) * 32;

    floatx4 acc[4][2] = {};

    // Staging: As = 8 chunks of 1KB (wave stages 2), Bs = 4 chunks (wave 1).
    const int srA0 = wave * 32 + (lane >> 2);
    const int srA1 = srA0 + 16;
    const int srB  = wave * 16 + (lane >> 2);
    const int skel = (lane & 3) * 8;
    const u16* Ap0 = A + (size_t)(bm + srA0) * K + skel;
    const u16* Ap1 = A + (size_t)(bm + srA1) * K + skel;
    const u16* Bp  = B + (size_t)(bn + srB)  * K + skel;
    u16* AsC0 = &As[(wave * 2 + 0) * 512];
    u16* AsC1 = &As[(wave * 2 + 1) * 512];
    u16* BsC  = &Bs[wave * 512];

    const int fr = lane & 15;
    const int fk = (lane >> 4) * 8;

    for (int k0 = 0; k0 < K; k0 += 32) {
        gl_lds16(Ap0 + k0, AsC0);
        gl_lds16(Ap1 + k0, AsC1);
        gl_lds16(Bp  + k0, BsC);
        __syncthreads();
        bf16x8 af[4], bf[2];
        #pragma unroll
        for (int i = 0; i < 4; i++)
            af[i] = *(const bf16x8*)&As[(qr + i * 16 + fr) * 32 + fk];
        #pragma unroll
        for (int j = 0; j < 2; j++)
            bf[j] = *(const bf16x8*)&Bs[(qc + j * 16 + fr) * 32 + fk];
        #pragma unroll
        for (int i = 0; i < 4; i++)
            #pragma unroll
            for (int j = 0; j < 2; j++)
                acc[i][j] = __builtin_amdgcn_mfma_f32_16x16x32_bf16(
                    af[i], bf[j], acc[i][j], 0, 0, 0);
        __syncthreads();
    }

    // C/D layout: col = lane&15, row = (lane>>4)*4 + r.
    const int cr = (lane >> 4) * 4;
    const int cc = lane & 15;
    #pragma unroll
    for (int i = 0; i < 4; i++) {
        #pragma unroll
        for (int j = 0; j < 2; j++) {
            const int row0 = bm + qr + i * 16 + cr;
            const int col  = bn + qc + j * 16 + cc;
            if (MODE == 0) {
                #pragma unroll
                for (int r = 0; r < 4; r++)
                    C[(size_t)(row0 + r) * N + col] = acc[i][j][r];
            } else {
                if (col < 1024) {
                    #pragma unroll
                    for (int r = 0; r < 4; r++)
                        Cb[(size_t)(row0 + r) * 1024 + col] = f2bf(acc[i][j][r]);
                } else {
                    ushort4 w;
                    w.x = f2bf(acc[i][j][0]); w.y = f2bf(acc[i][j][1]);
                    w.z = f2bf(acc[i][j][2]); w.w = f2bf(acc[i][j][3]);
                    *(ushort4*)&vT[(size_t)(col - 1024) * 2048 + row0] = w;
                }
            }
        }
    }
}

// NATTEN 7x7 on MFMA. Block = (q-head h, 8x8 pixel tile). 256 thr = 4 waves,
// wave = 16 queries (one M-tile). KV union window = fixed 14x14 at origin
// wu = clip(tile-3, 0, 18); neighbor index n = a*16 + b (a,b in window,
// b>=14 masked), K-dim 224 = 14 MFMA n-tiles.
//   S = Q K^T : A = Q (global frags), B = K rows (LDS [224][72], pad->no bc)
//   softmax in C-layout (rows spread over regs, cols over 16 lanes)
//   O^T = V^T P^T : A = V^T (LDS [64][224] from pre-transposed vT),
//                   B = P^T (per-wave 1KB LDS chunk, barrier-free)
__global__ __launch_bounds__(256) void natten_mfma(
    const u16* __restrict__ qkv, const u16* __restrict__ vT,
    u16* __restrict__ o)
{
    __shared__ __align__(16) u16 Ks[224 * 72];   // 32256 B
    __shared__ __align__(16) u16 Vs[64 * 224];   // 28672 B
    __shared__ __align__(16) u16 Pw[4 * 512];    //  4096 B
    const int h  = blockIdx.x;        // 0..11
    const int tb = blockIdx.y;        // 0..31
    const int g  = h & 3;             // kv head = h % 4
    const int batch = tb >> 4;
    const int ti = ((tb >> 2) & 3) * 8;
    const int tj = (tb & 3) * 8;
    const int wu_i = min(max(ti - 3, 0), 18);
    const int wu_j = min(max(tj - 3, 0), 18);
    const int tid = threadIdx.x, lane = tid & 63, wave = tid >> 6;
    const int pixbase = batch << 10;

    // ---- stage K rows: n = a*16+b, b clamped to 13 for pad cols (masked).
    for (int c = tid; c < 1792; c += 256) {           // 224 rows x 8 segs
        int n = c >> 3, seg = (c & 7) * 8;
        int a = n >> 4, b = min(n & 15, 13);
        int pix = pixbase + (wu_i + a) * 32 + wu_j + b;
        *(uint4*)&Ks[n * 72 + seg] =
            *(const uint4*)&qkv[(size_t)pix * 1024 + 768 + g * 64 + seg];
    }
    // ---- stage V^T[d][n] (scalar: vT cols are 2B-aligned only); pad n -> 0.
    for (int c = tid; c < 14336; c += 256) {          // 64 d x 224 n
        int d = c / 224, n = c % 224;
        int a = n >> 4, b = n & 15;
        u16 val = 0;
        if (b < 14) {
            int pix = pixbase + (wu_i + a) * 32 + wu_j + b;
            val = vT[(size_t)(g * 64 + d) * 2048 + pix];
        }
        Vs[d * 224 + n] = val;
    }
    __syncthreads();

    const int fr = lane & 15;
    const int fk = (lane >> 4) * 8;

    // Q A-frags from global: m = fr -> query q = wave*16 + fr.
    bf16x8 aq0, aq1;
    {
        int qq = wave * 16 + fr;
        int pixq = pixbase + (ti + (qq >> 3)) * 32 + tj + (qq & 7);
        const u16* qp = &qkv[(size_t)pixq * 1024 + h * 64];
        aq0 = *(const bf16x8*)(qp + fk);
        aq1 = *(const bf16x8*)(qp + 32 + fk);
    }

    // Per-r window bounds (row in C-layout = (lane>>4)*4 + r).
    bool colok[4]; int tlo[4], thi[4];
    #pragma unroll
    for (int r = 0; r < 4; r++) {
        int qq = wave * 16 + (lane >> 4) * 4 + r;
        int qi = ti + (qq >> 3), qj = tj + (qq & 7);
        int si = min(max(qi - 3, 0), 25);
        int sj = min(max(qj - 3, 0), 25);
        colok[r] = (fr < 14) && (wu_j + fr >= sj) && (wu_j + fr <= sj + 6);
        tlo[r] = si - wu_i; thi[r] = tlo[r] + 6;
    }

    // ---- QK^T + mask (scale 1/8 folded here).
    float s[14][4];
    float mx[4] = {-1e30f, -1e30f, -1e30f, -1e30f};
    #pragma unroll
    for (int t = 0; t < 14; t++) {
        bf16x8 bk0 = *(const bf16x8*)&Ks[(t * 16 + fr) * 72 + fk];
        bf16x8 bk1 = *(const bf16x8*)&Ks[(t * 16 + fr) * 72 + 32 + fk];
        floatx4 a4 = {};
        a4 = __builtin_amdgcn_mfma_f32_16x16x32_bf16(aq0, bk0, a4, 0, 0, 0);
        a4 = __builtin_amdgcn_mfma_f32_16x16x32_bf16(aq1, bk1, a4, 0, 0, 0);
        #pragma unroll
        for (int r = 0; r < 4; r++) {
            bool v = colok[r] && (t >= tlo[r]) && (t <= thi[r]);
            s[t][r] = v ? a4[r] * 0.125f : -1e30f;
            mx[r] = fmaxf(mx[r], s[t][r]);
        }
    }
    // ---- softmax (row = fixed per (quad,r); reduce over 16 col-lanes).
    #pragma unroll
    for (int r = 0; r < 4; r++) {
        mx[r] = fmaxf(mx[r], __shfl_xor(mx[r], 1));
        mx[r] = fmaxf(mx[r], __shfl_xor(mx[r], 2));
        mx[r] = fmaxf(mx[r], __shfl_xor(mx[r], 4));
        mx[r] = fmaxf(mx[r], __shfl_xor(mx[r], 8));
    }
    float l[4] = {0.f, 0.f, 0.f, 0.f};
    #pragma unroll
    for (int t = 0; t < 14; t++)
        #pragma unroll
        for (int r = 0; r < 4; r++) {
            float p = __expf(s[t][r] - mx[r]);
            s[t][r] = p; l[r] += p;
        }
    #pragma unroll
    for (int r = 0; r < 4; r++) {
        l[r] += __shfl_xor(l[r], 1);
        l[r] += __shfl_xor(l[r], 2);
        l[r] += __shfl_xor(l[r], 4);
        l[r] += __shfl_xor(l[r], 8);
    }
    float rinv[4];
    #pragma unroll
    for (int r = 0; r < 4; r++) rinv[r] = 1.0f / l[r];

    // ---- O^T = V^T P^T, K chunks of 32 n. Per-wave Pw buffer, barrier-free
    // (cross-lane within one wave's instruction stream; compiler lgkmcnt).
    u16* pw = &Pw[wave * 512];
    floatx4 oacc[4] = {};
    #pragma unroll
    for (int kc = 0; kc < 7; kc++) {
        #pragma unroll
        for (int tt = 0; tt < 2; tt++) {
            int t = kc * 2 + tt;
            #pragma unroll
            for (int r = 0; r < 4; r++)
                pw[((lane >> 4) * 4 + r) * 32 + tt * 16 + fr] =
                    f2bf(s[t][r] * rinv[r]);
        }
        bf16x8 bp = *(const bf16x8*)&pw[fr * 32 + fk];
        #pragma unroll
        for (int u = 0; u < 4; u++) {
            bf16x8 av = *(const bf16x8*)&Vs[(u * 16 + fr) * 224 + kc * 32 + fk];
            oacc[u] = __builtin_amdgcn_mfma_f32_16x16x32_bf16(av, bp, oacc[u], 0, 0, 0);
        }
    }

    // ---- write O: lane has col q = fr, rows d = u*16 + (lane>>4)*4 + r.
    {
        int qq = wave * 16 + fr;
        int pixq = pixbase + (ti + (qq >> 3)) * 32 + tj + (qq & 7);
        u16* op = &o[(size_t)pixq * 768 + h * 64];
        #pragma unroll
        for (int u = 0; u < 4; u++) {
            ushort4 w;
            w.x = f2bf(oacc[u][0]); w.y = f2bf(oacc[u][1]);
            w.z = f2bf(oacc[u][2]); w.w = f2bf(oacc[u][3]);
            *(ushort4*)(op + u * 16 + (lane >> 4) * 4) = w;
        }
    }
}

extern "C" void kernel_launch(void* const* d_in, const int* in_sizes, int n_in,
                              void* d_out, int out_size, void* d_ws, size_t ws_size,
                              hipStream_t stream)
{
    const float* x     = (const float*)d_in[0];   // (2048, 768)
    const float* w_qkv = (const float*)d_in[1];   // (1280, 768)
    const float* w_out = (const float*)d_in[2];   // (768, 768)
    float* out = (float*)d_out;                   // (2048, 768) fp32

    char* ws = (char*)d_ws;
    u16* qkvb = (u16*)ws; ws += (size_t)2048 * 1024 * 2;   // q|k bf16, 4 MB
    u16* vTb  = (u16*)ws; ws += (size_t)256 * 2048 * 2 + 64; // v^T bf16, 1 MB
    u16* xb   = (u16*)ws; ws += (size_t)2048 * 768 * 2;    // 3 MB
    u16* w1b  = (u16*)ws; ws += (size_t)1280 * 768 * 2;    // 2 MB
    u16* w2b  = (u16*)ws; ws += (size_t)768 * 768 * 2;     // 1.1 MB
    u16* ob   = (u16*)ws;                                  // 3 MB

    convert_kernel<<<dim3(3072), dim3(256), 0, stream>>>(x, w_qkv, w_out, xb, w1b, w2b);

    // qkv = x @ w_qkv^T -> bf16 q|k (cols<1024) + transposed v (cols>=1024)
    gemm_nt<1><<<dim3(1280 / 64, 2048 / 128), dim3(256), 0, stream>>>(
        xb, w1b, nullptr, qkvb, vTb, 2048, 1280, 768);

    natten_mfma<<<dim3(12, 32), dim3(256), 0, stream>>>(qkvb, vTb, ob);

    // out = o @ w_out^T (fp32 out)
    gemm_nt<0><<<dim3(768 / 64, 2048 / 128), dim3(256), 0, stream>>>(
        ob, w2b, out, nullptr, nullptr, 2048, 768, 768);
}

// Round 4
// 108.675 us; speedup vs baseline: 2.1315x; 1.1328x over previous
//
#include <hip/hip_runtime.h>
#include <hip/hip_bf16.h>

// ---------------------------------------------------------------------------
// NattenBlock: qkv GEMM -> 7x7 neighborhood attention (GQA 12q/4kv, D=64)
//              -> out GEMM.  2048 pixels (2x32x32), d_model 768.
// Round 4: GEMMs retiled 64x64 / BK=128 (6 iters, 4x fewer barrier drains,
// 640/384 blocks for 2.5x co-residency -> m114 overlap engages). Natten V^T
// staging addressing rewritten shift/mask (no div/mod). Everything bf16 MFMA.
// ---------------------------------------------------------------------------

typedef __attribute__((ext_vector_type(8))) __bf16 bf16x8;
typedef __attribute__((ext_vector_type(4))) float floatx4;
typedef unsigned short u16;

__device__ inline u16 f2bf(float f) {
    union { float f; unsigned u; } v; v.f = f;
    return (u16)((v.u + 0x7fff + ((v.u >> 16) & 1)) >> 16);   // RNE
}

__device__ inline void gl_lds16(const void* g, void* l) {
    __builtin_amdgcn_global_load_lds(
        (const __attribute__((address_space(1))) void*)g,
        (__attribute__((address_space(3))) void*)l, 16, 0, 0);
}

// fp32 -> bf16 for x (393216 f4), w_qkv (245760 f4), w_out (147456 f4).
__global__ __launch_bounds__(256) void convert_kernel(
    const float* __restrict__ x, const float* __restrict__ w1,
    const float* __restrict__ w2, u16* __restrict__ xb,
    u16* __restrict__ w1b, u16* __restrict__ w2b)
{
    int t = blockIdx.x * blockDim.x + threadIdx.x;   // 0..786431
    const float* s; u16* d;
    if (t < 393216)      { s = x;  d = xb; }
    else if (t < 638976) { s = w1; d = w1b; t -= 393216; }
    else                 { s = w2; d = w2b; t -= 638976; }
    float4 v = ((const float4*)s)[t];
    ushort4 o;
    o.x = f2bf(v.x); o.y = f2bf(v.y); o.z = f2bf(v.z); o.w = f2bf(v.w);
    ((ushort4*)d)[t] = o;
}

// C = A[M,K] @ B[N,K]^T, bf16 in, fp32 accum. Tile 64Mx64N, BK=128 staged as
// 4 sub-tiles of m97 layout [64][32] (keeps global_load_lds dest contiguity).
// 256 thr = 4 waves; waves 0,1 stage As, waves 2,3 stage Bs (8 chunks each).
// Wave quadrant 32x32 = 2x2 MFMA tiles of 16x16x32. K%128==0.
// MODE 0: fp32 C[M,N]. MODE 1 (qkv): col<1024 -> bf16 Cb[row*1024+col],
// col>=1024 -> transposed bf16 vT[(col-1024)*2048 + row] (ushort4/acc-tile).
template<int MODE>
__global__ __launch_bounds__(256) void gemm_nt(
    const u16* __restrict__ A, const u16* __restrict__ B,
    float* __restrict__ C, u16* __restrict__ Cb, u16* __restrict__ vT,
    int M, int N, int K)
{
    __shared__ __align__(16) u16 As[4 * 64 * 32];   // 16 KB, [kc][m][32]
    __shared__ __align__(16) u16 Bs[4 * 64 * 32];   // 16 KB, [kc][n][32]
    const int tid = threadIdx.x;
    const int lane = tid & 63;
    const int wave = tid >> 6;
    const int bm = blockIdx.y * 64;
    const int bn = blockIdx.x * 64;
    const int qr = (wave >> 1) * 32;
    const int qc = (wave & 1) * 32;

    floatx4 acc[2][2] = {};

    // Staging pointers: chunk c = (wave&1)*8 + cc, kc = c&3, rg = c>>2;
    // lane: row = rg*16 + (lane>>2), kofs = kc*32 + (lane&3)*8.
    const u16* Xsrc = (wave < 2) ? A : B;
    const int   bx  = (wave < 2) ? bm : bn;
    u16* Xlds       = (wave < 2) ? As : Bs;
    const int half  = wave & 1;
    const int l2 = lane >> 2;
    const int l3 = (lane & 3) * 8;
    const u16* gptr[8];
    u16* lptr[8];
    #pragma unroll
    for (int cc = 0; cc < 8; cc++) {
        int c = half * 8 + cc, kc = c & 3, rg = c >> 2;
        gptr[cc] = Xsrc + (size_t)(bx + rg * 16 + l2) * K + kc * 32 + l3;
        lptr[cc] = Xlds + kc * 2048 + rg * 512;
    }

    const int fr = lane & 15;
    const int fk = (lane >> 4) * 8;

    for (int k0 = 0; k0 < K; k0 += 128) {
        #pragma unroll
        for (int cc = 0; cc < 8; cc++)
            gl_lds16(gptr[cc] + k0, lptr[cc]);
        __syncthreads();
        #pragma unroll
        for (int kc = 0; kc < 4; kc++) {
            bf16x8 af0 = *(const bf16x8*)&As[kc * 2048 + (qr +      fr) * 32 + fk];
            bf16x8 af1 = *(const bf16x8*)&As[kc * 2048 + (qr + 16 + fr) * 32 + fk];
            bf16x8 bf0 = *(const bf16x8*)&Bs[kc * 2048 + (qc +      fr) * 32 + fk];
            bf16x8 bf1 = *(const bf16x8*)&Bs[kc * 2048 + (qc + 16 + fr) * 32 + fk];
            acc[0][0] = __builtin_amdgcn_mfma_f32_16x16x32_bf16(af0, bf0, acc[0][0], 0, 0, 0);
            acc[0][1] = __builtin_amdgcn_mfma_f32_16x16x32_bf16(af0, bf1, acc[0][1], 0, 0, 0);
            acc[1][0] = __builtin_amdgcn_mfma_f32_16x16x32_bf16(af1, bf0, acc[1][0], 0, 0, 0);
            acc[1][1] = __builtin_amdgcn_mfma_f32_16x16x32_bf16(af1, bf1, acc[1][1], 0, 0, 0);
        }
        __syncthreads();
    }

    // C/D layout: col = lane&15, row = (lane>>4)*4 + r.
    const int cr = (lane >> 4) * 4;
    const int ccol = lane & 15;
    #pragma unroll
    for (int i = 0; i < 2; i++) {
        #pragma unroll
        for (int j = 0; j < 2; j++) {
            const int row0 = bm + qr + i * 16 + cr;
            const int col  = bn + qc + j * 16 + ccol;
            if (MODE == 0) {
                #pragma unroll
                for (int r = 0; r < 4; r++)
                    C[(size_t)(row0 + r) * N + col] = acc[i][j][r];
            } else {
                if (col < 1024) {
                    #pragma unroll
                    for (int r = 0; r < 4; r++)
                        Cb[(size_t)(row0 + r) * 1024 + col] = f2bf(acc[i][j][r]);
                } else {
                    ushort4 w;
                    w.x = f2bf(acc[i][j][0]); w.y = f2bf(acc[i][j][1]);
                    w.z = f2bf(acc[i][j][2]); w.w = f2bf(acc[i][j][3]);
                    *(ushort4*)&vT[(size_t)(col - 1024) * 2048 + row0] = w;
                }
            }
        }
    }
}

// NATTEN 7x7 on MFMA. Block = (q-head h, 8x8 pixel tile). 256 thr = 4 waves,
// wave = 16 queries. KV union = 14x14 patch at wu = clip(tile-3, 0, 18);
// neighbor n = a*16 + b (b>=14 / a>=14 masked), K-dim 224 = 14 n-tiles.
__global__ __launch_bounds__(256) void natten_mfma(
    const u16* __restrict__ qkv, const u16* __restrict__ vT,
    u16* __restrict__ o)
{
    __shared__ __align__(16) u16 Ks[224 * 72];   // 32256 B
    __shared__ __align__(16) u16 Vs[64 * 224];   // 28672 B
    __shared__ __align__(16) u16 Pw[4 * 512];    //  4096 B
    const int h  = blockIdx.x;        // 0..11
    const int tb = blockIdx.y;        // 0..31
    const int g  = h & 3;             // kv head = h % 4
    const int batch = tb >> 4;
    const int ti = ((tb >> 2) & 3) * 8;
    const int tj = (tb & 3) * 8;
    const int wu_i = min(max(ti - 3, 0), 18);
    const int wu_j = min(max(tj - 3, 0), 18);
    const int tid = threadIdx.x, lane = tid & 63, wave = tid >> 6;
    const int pixbase = batch << 10;

    // ---- stage K rows: n = a*16+b, b clamped to 13 for pad cols (masked).
    for (int c = tid; c < 1792; c += 256) {           // 224 rows x 8 segs
        int n = c >> 3, seg = (c & 7) * 8;
        int a = n >> 4, b = min(n & 15, 13);
        int pix = pixbase + (wu_i + a) * 32 + wu_j + b;
        *(uint4*)&Ks[n * 72 + seg] =
            *(const uint4*)&qkv[(size_t)pix * 1024 + 768 + g * 64 + seg];
    }
    // ---- stage V^T[d][n]: wave w -> d in [16w,16w+16); lane: b = lane&15,
    // a = (lane>>4) + 4*rr  (n = rr*64 + lane = a*16+b). Shift/mask only.
    {
        const int b  = lane & 15;
        const int ar = lane >> 4;
        bool vok[4]; int voff[4];
        #pragma unroll
        for (int rr = 0; rr < 4; rr++) {
            int a = ar + rr * 4;
            vok[rr]  = (a < 14) && (b < 14);
            voff[rr] = (wu_i + a) * 32 + wu_j + b;
        }
        const u16* vsrc = &vT[(size_t)(g * 64 + wave * 16) * 2048 + pixbase];
        #pragma unroll 4
        for (int dd = 0; dd < 16; dd++) {
            #pragma unroll
            for (int rr = 0; rr < 4; rr++) {
                int a = ar + rr * 4;
                if (a < 14)
                    Vs[(wave * 16 + dd) * 224 + rr * 64 + lane] =
                        vok[rr] ? vsrc[voff[rr]] : (u16)0;
            }
            vsrc += 2048;
        }
    }
    __syncthreads();

    const int fr = lane & 15;
    const int fk = (lane >> 4) * 8;

    // Q A-frags from global: query q = wave*16 + fr.
    bf16x8 aq0, aq1;
    {
        int qq = wave * 16 + fr;
        int pixq = pixbase + (ti + (qq >> 3)) * 32 + tj + (qq & 7);
        const u16* qp = &qkv[(size_t)pixq * 1024 + h * 64];
        aq0 = *(const bf16x8*)(qp + fk);
        aq1 = *(const bf16x8*)(qp + 32 + fk);
    }

    // Per-r window bounds (row in C-layout = (lane>>4)*4 + r).
    bool colok[4]; int tlo[4], thi[4];
    #pragma unroll
    for (int r = 0; r < 4; r++) {
        int qq = wave * 16 + (lane >> 4) * 4 + r;
        int qi = ti + (qq >> 3), qj = tj + (qq & 7);
        int si = min(max(qi - 3, 0), 25);
        int sj = min(max(qj - 3, 0), 25);
        colok[r] = (fr < 14) && (wu_j + fr >= sj) && (wu_j + fr <= sj + 6);
        tlo[r] = si - wu_i; thi[r] = tlo[r] + 6;
    }

    // ---- QK^T + mask (scale 1/8 folded here).
    float s[14][4];
    float mx[4] = {-1e30f, -1e30f, -1e30f, -1e30f};
    #pragma unroll
    for (int t = 0; t < 14; t++) {
        bf16x8 bk0 = *(const bf16x8*)&Ks[(t * 16 + fr) * 72 + fk];
        bf16x8 bk1 = *(const bf16x8*)&Ks[(t * 16 + fr) * 72 + 32 + fk];
        floatx4 a4 = {};
        a4 = __builtin_amdgcn_mfma_f32_16x16x32_bf16(aq0, bk0, a4, 0, 0, 0);
        a4 = __builtin_amdgcn_mfma_f32_16x16x32_bf16(aq1, bk1, a4, 0, 0, 0);
        #pragma unroll
        for (int r = 0; r < 4; r++) {
            bool v = colok[r] && (t >= tlo[r]) && (t <= thi[r]);
            s[t][r] = v ? a4[r] * 0.125f : -1e30f;
            mx[r] = fmaxf(mx[r], s[t][r]);
        }
    }
    // ---- softmax (reduce over 16 col-lanes).
    #pragma unroll
    for (int r = 0; r < 4; r++) {
        mx[r] = fmaxf(mx[r], __shfl_xor(mx[r], 1));
        mx[r] = fmaxf(mx[r], __shfl_xor(mx[r], 2));
        mx[r] = fmaxf(mx[r], __shfl_xor(mx[r], 4));
        mx[r] = fmaxf(mx[r], __shfl_xor(mx[r], 8));
    }
    float l[4] = {0.f, 0.f, 0.f, 0.f};
    #pragma unroll
    for (int t = 0; t < 14; t++)
        #pragma unroll
        for (int r = 0; r < 4; r++) {
            float p = __expf(s[t][r] - mx[r]);
            s[t][r] = p; l[r] += p;
        }
    #pragma unroll
    for (int r = 0; r < 4; r++) {
        l[r] += __shfl_xor(l[r], 1);
        l[r] += __shfl_xor(l[r], 2);
        l[r] += __shfl_xor(l[r], 4);
        l[r] += __shfl_xor(l[r], 8);
    }
    float rinv[4];
    #pragma unroll
    for (int r = 0; r < 4; r++) rinv[r] = 1.0f / l[r];

    // ---- O^T = V^T P^T, per-wave Pw buffer (barrier-free within wave).
    u16* pw = &Pw[wave * 512];
    floatx4 oacc[4] = {};
    #pragma unroll
    for (int kc = 0; kc < 7; kc++) {
        #pragma unroll
        for (int tt = 0; tt < 2; tt++) {
            int t = kc * 2 + tt;
            #pragma unroll
            for (int r = 0; r < 4; r++)
                pw[((lane >> 4) * 4 + r) * 32 + tt * 16 + fr] =
                    f2bf(s[t][r] * rinv[r]);
        }
        bf16x8 bp = *(const bf16x8*)&pw[fr * 32 + fk];
        #pragma unroll
        for (int u = 0; u < 4; u++) {
            bf16x8 av = *(const bf16x8*)&Vs[(u * 16 + fr) * 224 + kc * 32 + fk];
            oacc[u] = __builtin_amdgcn_mfma_f32_16x16x32_bf16(av, bp, oacc[u], 0, 0, 0);
        }
    }

    // ---- write O: lane has col q = fr, rows d = u*16 + (lane>>4)*4 + r.
    {
        int qq = wave * 16 + fr;
        int pixq = pixbase + (ti + (qq >> 3)) * 32 + tj + (qq & 7);
        u16* op = &o[(size_t)pixq * 768 + h * 64];
        #pragma unroll
        for (int u = 0; u < 4; u++) {
            ushort4 w;
            w.x = f2bf(oacc[u][0]); w.y = f2bf(oacc[u][1]);
            w.z = f2bf(oacc[u][2]); w.w = f2bf(oacc[u][3]);
            *(ushort4*)(op + u * 16 + (lane >> 4) * 4) = w;
        }
    }
}

extern "C" void kernel_launch(void* const* d_in, const int* in_sizes, int n_in,
                              void* d_out, int out_size, void* d_ws, size_t ws_size,
                              hipStream_t stream)
{
    const float* x     = (const float*)d_in[0];   // (2048, 768)
    const float* w_qkv = (const float*)d_in[1];   // (1280, 768)
    const float* w_out = (const float*)d_in[2];   // (768, 768)
    float* out = (float*)d_out;                   // (2048, 768) fp32

    char* ws = (char*)d_ws;
    u16* qkvb = (u16*)ws; ws += (size_t)2048 * 1024 * 2;     // q|k bf16, 4 MB
    u16* vTb  = (u16*)ws; ws += (size_t)256 * 2048 * 2 + 64; // v^T bf16, 1 MB
    u16* xb   = (u16*)ws; ws += (size_t)2048 * 768 * 2;      // 3 MB
    u16* w1b  = (u16*)ws; ws += (size_t)1280 * 768 * 2;      // 2 MB
    u16* w2b  = (u16*)ws; ws += (size_t)768 * 768 * 2;       // 1.1 MB
    u16* ob   = (u16*)ws;                                    // 3 MB

    convert_kernel<<<dim3(3072), dim3(256), 0, stream>>>(x, w_qkv, w_out, xb, w1b, w2b);

    // qkv = x @ w_qkv^T -> bf16 q|k (cols<1024) + transposed v (cols>=1024)
    gemm_nt<1><<<dim3(1280 / 64, 2048 / 64), dim3(256), 0, stream>>>(
        xb, w1b, nullptr, qkvb, vTb, 2048, 1280, 768);

    natten_mfma<<<dim3(12, 32), dim3(256), 0, stream>>>(qkvb, vTb, ob);

    // out = o @ w_out^T (fp32 out)
    gemm_nt<0><<<dim3(768 / 64, 2048 / 64), dim3(256), 0, stream>>>(
        ob, w2b, out, nullptr, nullptr, 2048, 768, 768);
}